// Round 9
// baseline (200.818 us; speedup 1.0000x reference)
//
#include <hip/hip_runtime.h>

#define R_ 8
#define N_ 40000
#define F_ 128
#define E_ 160000
#define NE (R_ * E_)        // 1,280,000 edges
#define NBUK 625            // src>>6 buckets of 64 rows; 625*64 == 40000 exactly
#define CAP 2560            // fixed bucket capacity: mean 2048, sigma ~45 -> +11 sigma
#define FBLK 320            // edge chunks
#define FCHUNK 4000         // FBLK * FCHUNK == NE exactly
#define RELCHUNKS (E_ / FCHUNK)   // 40 chunks per relation -> a chunk is single-relation
#define FSTILE 16           // buckets per fillscan tile block

typedef unsigned short ushort;
typedef unsigned int uint;
typedef unsigned long long u64;
typedef __attribute__((ext_vector_type(8))) short bf16x8;
typedef __attribute__((ext_vector_type(4))) float f32x4;

// fp32 -> bf16 round-to-nearest-even (returns bit pattern)
__device__ __forceinline__ ushort f2bf(float x) {
    uint u = __float_as_uint(x);
    return (ushort)((u + 0x7fffu + ((u >> 16) & 1u)) >> 16);
}

// --- K1: fused independent prep (round-2 proven; plain cached loads —
//         NT here was the r7 regression: ent lines are touched by multiple
//         instructions and rely on L1/L2 reuse) ---
// blocks [0,625):    proj = ent @ W  via bf16 MFMA (64 rows/block)
// block  625:        rel_mat passthrough to out tail
// blocks [626,630):  alpha MLP (2 relations/block)
// blocks [630,950):  fillA — per-chunk bucket histogram (625 buckets of 64 rows)
__global__ __launch_bounds__(256) void fused_prep(
        const float* __restrict__ ent, const float* __restrict__ W,
        ushort* __restrict__ proj,
        const int* __restrict__ esrc,
        const float* __restrict__ rel, float* __restrict__ out_tail,
        const float* __restrict__ w1, const float* __restrict__ b1,
        const float* __restrict__ w2, float* __restrict__ alpha,
        int* __restrict__ hist) {
    __shared__ float smem[64 * F_];          // 32 KB; aliases as ushort Wt[128][128]
    const int t = threadIdx.x;
    const int b = blockIdx.x;
    if (b < 625) {
        ushort* Wt = (ushort*)smem;          // W^T bf16, chunk-XOR swizzle
#pragma unroll
        for (int p = 0; p < 16; ++p) {
            int k = p * 8 + (t >> 5);
            int c4 = (t & 31) * 4;
            float4 wv = *(const float4*)&W[k * F_ + c4];
#pragma unroll
            for (int i = 0; i < 4; ++i) {
                int col = c4 + i;
                float v = (i == 0) ? wv.x : (i == 1) ? wv.y : (i == 2) ? wv.z : wv.w;
                Wt[col * F_ + ((((k >> 3) ^ (col & 7)) << 3) | (k & 7))] = f2bf(v);
            }
        }
        __syncthreads();
        const int wv_ = t >> 6;              // wave 0..3
        const int lane = t & 63;
        const int m = lane & 15;
        const int q = (lane >> 4) & 3;
        const int row0 = b * 64 + wv_ * 16;
        bf16x8 afrag[4];
        const float* arow = ent + (size_t)(row0 + m) * F_;
#pragma unroll
        for (int kc = 0; kc < 4; ++kc) {
            float4 a0 = *(const float4*)&arow[kc * 32 + q * 8];
            float4 a1 = *(const float4*)&arow[kc * 32 + q * 8 + 4];
            bf16x8 a;
            a[0] = (short)f2bf(a0.x); a[1] = (short)f2bf(a0.y);
            a[2] = (short)f2bf(a0.z); a[3] = (short)f2bf(a0.w);
            a[4] = (short)f2bf(a1.x); a[5] = (short)f2bf(a1.y);
            a[6] = (short)f2bf(a1.z); a[7] = (short)f2bf(a1.w);
            afrag[kc] = a;
        }
        f32x4 acc[8];
#pragma unroll
        for (int ct = 0; ct < 8; ++ct) acc[ct] = (f32x4){0.f, 0.f, 0.f, 0.f};
#pragma unroll
        for (int ct = 0; ct < 8; ++ct) {
            int n = ct * 16 + m;
#pragma unroll
            for (int kc = 0; kc < 4; ++kc) {
                int chunk = kc * 4 + q;
                bf16x8 bfrag = *(const bf16x8*)&Wt[n * F_ + ((chunk ^ (n & 7)) << 3)];
                acc[ct] = __builtin_amdgcn_mfma_f32_16x16x32_bf16(afrag[kc], bfrag, acc[ct], 0, 0, 0);
            }
        }
#pragma unroll
        for (int ct = 0; ct < 8; ++ct) {
#pragma unroll
            for (int reg = 0; reg < 4; ++reg) {
                int row = row0 + q * 4 + reg;
                proj[(size_t)row * F_ + ct * 16 + m] = f2bf(acc[ct][reg]);
            }
        }
    } else if (b == 625) {
        ((float4*)out_tail)[t] = ((const float4*)rel)[t];   // 1024 floats
    } else if (b < 630) {
        int r = (b - 626) * 2 + (t >> 7);
        int o = t & 127;
        float s = 0.f;
#pragma unroll 8
        for (int f = 0; f < F_; ++f) s += rel[r * F_ + f] * w1[f * F_ + o];
        float h = tanhf(s + b1[o]);
        smem[t] = h * w2[o];
        __syncthreads();
        for (int off = 64; off > 0; off >>= 1) {
            if ((t & 127) < off) smem[t] += smem[t + off];
            __syncthreads();
        }
        if ((t & 127) == 0) alpha[r] = 1.f / (1.f + expf(-smem[t]));
    } else {
        // fillA: bucket histogram for chunk hb (LDS int atomics)
        int hb = b - 630;
        int* h = (int*)smem;
        for (int i = t; i < NBUK; i += 256) h[i] = 0;
        __syncthreads();
        int base = hb * FCHUNK;
        for (int i = t; i < FCHUNK; i += 256)
            atomicAdd(&h[esrc[base + i] >> 6], 1);
        __syncthreads();
        for (int i = t; i < NBUK; i += 256) hist[hb * NBUK + i] = h[i];   // coalesced
    }
}

// --- K2: tiled fillscan — load a [320][16]-bucket hist tile coalesced, shfl-scan
//         the 320-chunk prefix per bucket column in LDS, write TRANSPOSED
//         blockbase[chunk][bucket] coalesced. ---
__global__ __launch_bounds__(256) void fillscan_kernel(const int* __restrict__ hist,
                                                       int* __restrict__ blockbase,
                                                       int* __restrict__ total) {
    __shared__ int sc[FBLK][FSTILE + 1];     // 17-pad: conflict-free column walks
    __shared__ int tot_s[FSTILE];
    const int t = threadIdx.x;
    const int tb = blockIdx.x * FSTILE;
    // load tile (64 B coalesced runs per row)
    for (int i = t; i < FBLK * FSTILE; i += 256) {
        int f = i >> 4;
        int c = i & (FSTILE - 1);
        int bk = tb + c;
        sc[f][c] = (bk < NBUK) ? hist[f * NBUK + bk] : 0;
    }
    __syncthreads();
    // scan each bucket column: 4 waves x 4 columns, 5 shfl-64 segments + carry
    const int wv = t >> 6, lane = t & 63;
    for (int c = wv; c < FSTILE; c += 4) {
        int carry = 0;
#pragma unroll
        for (int seg = 0; seg < FBLK / 64; ++seg) {
            int f = seg * 64 + lane;
            int v = sc[f][c];
            int s = v;
#pragma unroll
            for (int off = 1; off < 64; off <<= 1) {
                int u = __shfl_up(s, off, 64);
                if (lane >= off) s += u;
            }
            sc[f][c] = carry + s - v;        // exclusive, bucket-relative
            carry += __shfl(s, 63, 64);
        }
        if (lane == 0) tot_s[c] = carry;
    }
    __syncthreads();
    // write out transposed layout, coalesced (64 B runs per chunk row)
    for (int i = t; i < FBLK * FSTILE; i += 256) {
        int f = i >> 4;
        int c = i & (FSTILE - 1);
        int bk = tb + c;
        if (bk < NBUK) blockbase[f * NBUK + bk] = sc[f][c];
    }
    if (t < FSTILE && tb + t < NBUK) total[tb + t] = tot_s[t];
}

// --- K3: fillB — stage edges bucket-ordered. Cached loads (esrc reused from
//         prep's fillA pass); NT STORE on the scattered staged writes: each
//         8-B staged line-touch is write-once with no reuse, so bypassing the
//         L2 write-allocate removes the ~64B-per-8B RFO phantom traffic. ---
__global__ __launch_bounds__(512) void fillB_kernel(const int* __restrict__ esrc,
                                                    const int* __restrict__ edst,
                                                    const float* __restrict__ eval_,
                                                    const float* __restrict__ alpha,
                                                    const int* __restrict__ blockbase,
                                                    u64* __restrict__ staged) {
    __shared__ int lcnt[NBUK];
    __shared__ int lbase[NBUK];
    int t = threadIdx.x, blk = blockIdx.x;
    for (int i = t; i < NBUK; i += 512) {
        lcnt[i] = 0;
        lbase[i] = i * CAP + blockbase[blk * NBUK + i];   // coalesced row read
    }
    __syncthreads();
    const float av = alpha[blk / RELCHUNKS];   // chunk is entirely one relation
    int base = blk * FCHUNK;
    for (int i = t; i < FCHUNK; i += 512) {
        int e = base + i;
        int s = esrc[e];
        int d = edst[e];
        float w = av * eval_[e];
        int bk = s >> 6;
        int rank = atomicAdd(&lcnt[bk], 1);
        int pos = lbase[bk] + rank;
        if (pos < (bk + 1) * CAP) {            // statistical overflow guard
            u64 v = ((u64)(uint)s << 32) | (u64)((uint)d | ((uint)f2bf(w) << 16));
            __builtin_nontemporal_store(v, &staged[pos]);
        }
    }
}

// --- K4: fillC+spmm fused (round-2 proven shape) — NT staged loads and NT out
//         stores keep L2 capacity for the proj gather (the measured bottleneck) ---
__global__ __launch_bounds__(512) void fillC_spmm(const u64* __restrict__ staged,
                                                  const int* __restrict__ total,
                                                  const ushort* __restrict__ proj,
                                                  float* __restrict__ out) {
    __shared__ uint2 raw[CAP];       // 20 KB
    __shared__ uint  srt[CAP];       // 10 KB
    __shared__ int cnt[64], cur[64], rs[65];
    const int b = blockIdx.x, t = threadIdx.x;
    int n = total[b];
    if (n > CAP) n = CAP;
    if (t < 64) cnt[t] = 0;
    __syncthreads();
    const u64* seg64 = staged + (size_t)b * CAP;
    for (int i = t; i < n; i += 512) {
        u64 v = __builtin_nontemporal_load(&seg64[i]);
        uint2 e = make_uint2((uint)v, (uint)(v >> 32));
        raw[i] = e;
        atomicAdd(&cnt[e.y & 63], 1);
    }
    __syncthreads();
    if (t < 64) cur[t] = cnt[t];
    __syncthreads();
    for (int off = 1; off < 64; off <<= 1) {
        int v = (t < 64 && t >= off) ? cur[t - off] : 0;
        __syncthreads();
        if (t < 64) cur[t] += v;
        __syncthreads();
    }
    if (t < 64) {
        rs[t + 1] = cur[t];                    // inclusive -> row end
        if (t == 0) rs[0] = 0;
        cur[t] -= cnt[t];                      // exclusive row start
    }
    __syncthreads();
    for (int i = t; i < n; i += 512) {
        uint2 e = raw[i];
        int pos = atomicAdd(&cur[e.y & 63], 1);
        srt[pos] = e.x;
    }
    __syncthreads();
    // spmm: 8 waves, wave w owns rows w*8 .. w*8+7
    const int wv = t >> 6;
    const int lane = t & 63;
    for (int rr = 0; rr < 8; ++rr) {
        int r = wv * 8 + rr;
        int beg = rs[r], end = rs[r + 1];
        float ax0 = 0.f, ay0 = 0.f, ax1 = 0.f, ay1 = 0.f;
        int j = beg;
        for (; j + 8 <= end; j += 8) {         // 8 gathers in flight
            uint e[8], u[8];
#pragma unroll
            for (int k = 0; k < 8; ++k) e[k] = srt[j + k];
#pragma unroll
            for (int k = 0; k < 8; ++k)
                u[k] = *(const uint*)&proj[((e[k] & 0xffffu) << 7) + 2 * lane];
#pragma unroll
            for (int k = 0; k < 8; ++k) {
                float w = __uint_as_float(e[k] & 0xffff0000u);
                if (k & 1) {
                    ax1 += w * __uint_as_float(u[k] << 16);
                    ay1 += w * __uint_as_float(u[k] & 0xffff0000u);
                } else {
                    ax0 += w * __uint_as_float(u[k] << 16);
                    ay0 += w * __uint_as_float(u[k] & 0xffff0000u);
                }
            }
        }
        for (; j < end; ++j) {
            uint e = srt[j];
            uint u = *(const uint*)&proj[((e & 0xffffu) << 7) + 2 * lane];
            float w = __uint_as_float(e & 0xffff0000u);
            ax0 += w * __uint_as_float(u << 16);
            ay0 += w * __uint_as_float(u & 0xffff0000u);
        }
        u64 pv = ((u64)__float_as_uint(ay0 + ay1) << 32) | (u64)__float_as_uint(ax0 + ax1);
        __builtin_nontemporal_store(pv,
            (u64*)&out[(((size_t)b * 64 + r) << 7) + 2 * lane]);
    }
}

extern "C" void kernel_launch(void* const* d_in, const int* in_sizes, int n_in,
                              void* d_out, int out_size, void* d_ws, size_t ws_size,
                              hipStream_t stream) {
    const float* ent   = (const float*)d_in[0];
    const float* rel   = (const float*)d_in[1];
    const int*   esrc  = (const int*)d_in[2];
    const int*   edst  = (const int*)d_in[3];
    const float* eval_ = (const float*)d_in[4];
    const float* went  = (const float*)d_in[5];
    const float* w1    = (const float*)d_in[6];
    const float* b1    = (const float*)d_in[7];
    const float* w2    = (const float*)d_in[8];

    float* out      = (float*)d_out;
    float* out_tail = out + (size_t)N_ * F_;

    char* ws = (char*)d_ws;
    size_t off = 0;
    ushort* proj      = (ushort*)(ws + off); off += (size_t)N_ * F_ * 2;       // 10.24 MB
    u64*    staged    = (u64*)(ws + off);    off += (size_t)NBUK * CAP * 8;    // 12.80 MB
    float*  alpha     = (float*)(ws + off);  off += 256;
    int*    hist      = (int*)(ws + off);    off += (size_t)FBLK * NBUK * 4;   // 800 KB
    int*    blockbase = (int*)(ws + off);    off += (size_t)FBLK * NBUK * 4;   // 800 KB (transposed)
    int*    total     = (int*)(ws + off);    off += (size_t)(NBUK + 7) * 4;

    fused_prep<<<950, 256, 0, stream>>>(ent, went, proj, esrc,
                                        rel, out_tail, w1, b1, w2, alpha, hist);
    fillscan_kernel<<<(NBUK + FSTILE - 1) / FSTILE, 256, 0, stream>>>(hist, blockbase, total);
    fillB_kernel<<<FBLK, 512, 0, stream>>>(esrc, edst, eval_, alpha, blockbase, staged);
    fillC_spmm<<<NBUK, 512, 0, stream>>>(staged, total, proj, out);
}

// Round 10
// 178.030 us; speedup vs baseline: 1.1280x; 1.1280x over previous
//
#include <hip/hip_runtime.h>

#define R_ 8
#define N_ 40000
#define F_ 128
#define E_ 160000
#define NE (R_ * E_)        // 1,280,000 edges
#define NBUK 625            // src>>6 buckets of 64 rows; 625*64 == 40000 exactly
#define CAP 2560            // fixed bucket capacity: mean 2048, sigma ~45 -> +11 sigma
#define FBLK 320            // edge chunks
#define FCHUNK 4000         // FBLK * FCHUNK == NE exactly
#define RELCHUNKS (E_ / FCHUNK)   // 40 chunks per relation -> a chunk is single-relation
#define FSTILE 16           // buckets per fillscan tile block

typedef unsigned short ushort;
typedef unsigned int uint;
typedef unsigned long long u64;
typedef __attribute__((ext_vector_type(8))) short bf16x8;
typedef __attribute__((ext_vector_type(4))) float f32x4;

// fp32 -> bf16 round-to-nearest-even (returns bit pattern)
__device__ __forceinline__ ushort f2bf(float x) {
    uint u = __float_as_uint(x);
    return (ushort)((u + 0x7fffu + ((u >> 16) & 1u)) >> 16);
}

// --- K1: fused independent prep (round-2 verbatim — plain cached loads) ---
// blocks [0,625):    proj = ent @ W  via bf16 MFMA (64 rows/block)
// block  625:        rel_mat passthrough to out tail
// blocks [626,630):  alpha MLP (2 relations/block)
// blocks [630,950):  fillA — per-chunk bucket histogram (625 buckets of 64 rows)
__global__ __launch_bounds__(256) void fused_prep(
        const float* __restrict__ ent, const float* __restrict__ W,
        ushort* __restrict__ proj,
        const int* __restrict__ esrc,
        const float* __restrict__ rel, float* __restrict__ out_tail,
        const float* __restrict__ w1, const float* __restrict__ b1,
        const float* __restrict__ w2, float* __restrict__ alpha,
        int* __restrict__ hist) {
    __shared__ float smem[64 * F_];          // 32 KB; aliases as ushort Wt[128][128]
    const int t = threadIdx.x;
    const int b = blockIdx.x;
    if (b < 625) {
        ushort* Wt = (ushort*)smem;          // W^T bf16, chunk-XOR swizzle
#pragma unroll
        for (int p = 0; p < 16; ++p) {
            int k = p * 8 + (t >> 5);
            int c4 = (t & 31) * 4;
            float4 wv = *(const float4*)&W[k * F_ + c4];
#pragma unroll
            for (int i = 0; i < 4; ++i) {
                int col = c4 + i;
                float v = (i == 0) ? wv.x : (i == 1) ? wv.y : (i == 2) ? wv.z : wv.w;
                Wt[col * F_ + ((((k >> 3) ^ (col & 7)) << 3) | (k & 7))] = f2bf(v);
            }
        }
        __syncthreads();
        const int wv_ = t >> 6;              // wave 0..3
        const int lane = t & 63;
        const int m = lane & 15;
        const int q = (lane >> 4) & 3;
        const int row0 = b * 64 + wv_ * 16;
        bf16x8 afrag[4];
        const float* arow = ent + (size_t)(row0 + m) * F_;
#pragma unroll
        for (int kc = 0; kc < 4; ++kc) {
            float4 a0 = *(const float4*)&arow[kc * 32 + q * 8];
            float4 a1 = *(const float4*)&arow[kc * 32 + q * 8 + 4];
            bf16x8 a;
            a[0] = (short)f2bf(a0.x); a[1] = (short)f2bf(a0.y);
            a[2] = (short)f2bf(a0.z); a[3] = (short)f2bf(a0.w);
            a[4] = (short)f2bf(a1.x); a[5] = (short)f2bf(a1.y);
            a[6] = (short)f2bf(a1.z); a[7] = (short)f2bf(a1.w);
            afrag[kc] = a;
        }
        f32x4 acc[8];
#pragma unroll
        for (int ct = 0; ct < 8; ++ct) acc[ct] = (f32x4){0.f, 0.f, 0.f, 0.f};
#pragma unroll
        for (int ct = 0; ct < 8; ++ct) {
            int n = ct * 16 + m;
#pragma unroll
            for (int kc = 0; kc < 4; ++kc) {
                int chunk = kc * 4 + q;
                bf16x8 bfrag = *(const bf16x8*)&Wt[n * F_ + ((chunk ^ (n & 7)) << 3)];
                acc[ct] = __builtin_amdgcn_mfma_f32_16x16x32_bf16(afrag[kc], bfrag, acc[ct], 0, 0, 0);
            }
        }
#pragma unroll
        for (int ct = 0; ct < 8; ++ct) {
#pragma unroll
            for (int reg = 0; reg < 4; ++reg) {
                int row = row0 + q * 4 + reg;
                proj[(size_t)row * F_ + ct * 16 + m] = f2bf(acc[ct][reg]);
            }
        }
    } else if (b == 625) {
        ((float4*)out_tail)[t] = ((const float4*)rel)[t];   // 1024 floats
    } else if (b < 630) {
        int r = (b - 626) * 2 + (t >> 7);
        int o = t & 127;
        float s = 0.f;
#pragma unroll 8
        for (int f = 0; f < F_; ++f) s += rel[r * F_ + f] * w1[f * F_ + o];
        float h = tanhf(s + b1[o]);
        smem[t] = h * w2[o];
        __syncthreads();
        for (int off = 64; off > 0; off >>= 1) {
            if ((t & 127) < off) smem[t] += smem[t + off];
            __syncthreads();
        }
        if ((t & 127) == 0) alpha[r] = 1.f / (1.f + expf(-smem[t]));
    } else {
        // fillA: bucket histogram for chunk hb (LDS int atomics)
        int hb = b - 630;
        int* h = (int*)smem;
        for (int i = t; i < NBUK; i += 256) h[i] = 0;
        __syncthreads();
        int base = hb * FCHUNK;
        for (int i = t; i < FCHUNK; i += 256)
            atomicAdd(&h[esrc[base + i] >> 6], 1);
        __syncthreads();
        for (int i = t; i < NBUK; i += 256) hist[hb * NBUK + i] = h[i];   // coalesced
    }
}

// --- K2: tiled fillscan — load a [320][16]-bucket hist tile coalesced, shfl-scan
//         the 320-chunk prefix per bucket column in LDS, write TRANSPOSED
//         blockbase[chunk][bucket] coalesced. (ran correct in r7/r9) ---
__global__ __launch_bounds__(256) void fillscan_kernel(const int* __restrict__ hist,
                                                       int* __restrict__ blockbase,
                                                       int* __restrict__ total) {
    __shared__ int sc[FBLK][FSTILE + 1];     // 17-pad: conflict-free column walks
    __shared__ int tot_s[FSTILE];
    const int t = threadIdx.x;
    const int tb = blockIdx.x * FSTILE;
    // load tile (64 B coalesced runs per row)
    for (int i = t; i < FBLK * FSTILE; i += 256) {
        int f = i >> 4;
        int c = i & (FSTILE - 1);
        int bk = tb + c;
        sc[f][c] = (bk < NBUK) ? hist[f * NBUK + bk] : 0;
    }
    __syncthreads();
    // scan each bucket column: 4 waves x 4 columns, 5 shfl-64 segments + carry
    const int wv = t >> 6, lane = t & 63;
    for (int c = wv; c < FSTILE; c += 4) {
        int carry = 0;
#pragma unroll
        for (int seg = 0; seg < FBLK / 64; ++seg) {
            int f = seg * 64 + lane;
            int v = sc[f][c];
            int s = v;
#pragma unroll
            for (int off = 1; off < 64; off <<= 1) {
                int u = __shfl_up(s, off, 64);
                if (lane >= off) s += u;
            }
            sc[f][c] = carry + s - v;        // exclusive, bucket-relative
            carry += __shfl(s, 63, 64);
        }
        if (lane == 0) tot_s[c] = carry;
    }
    __syncthreads();
    // write out transposed layout, coalesced (64 B runs per chunk row)
    for (int i = t; i < FBLK * FSTILE; i += 256) {
        int f = i >> 4;
        int c = i & (FSTILE - 1);
        int bk = tb + c;
        if (bk < NBUK) blockbase[f * NBUK + bk] = sc[f][c];
    }
    if (t < FSTILE && tb + t < NBUK) total[tb + t] = tot_s[t];
}

// --- K3: fillB — r2 verbatim except the blockbase read is now the coalesced
//         transposed row. Plain cached loads; PLAIN staged stores (r9 lesson:
//         NT store defeats L2 write-combining of the semi-clustered writes). ---
__global__ __launch_bounds__(256) void fillB_kernel(const int* __restrict__ esrc,
                                                    const int* __restrict__ edst,
                                                    const float* __restrict__ eval_,
                                                    const float* __restrict__ alpha,
                                                    const int* __restrict__ blockbase,
                                                    u64* __restrict__ staged) {
    __shared__ int lcnt[NBUK];
    __shared__ int lbase[NBUK];
    int t = threadIdx.x, blk = blockIdx.x;
    for (int i = t; i < NBUK; i += 256) {
        lcnt[i] = 0;
        lbase[i] = i * CAP + blockbase[blk * NBUK + i];   // coalesced row read
    }
    __syncthreads();
    const float av = alpha[blk / RELCHUNKS];   // chunk is entirely one relation
    int base = blk * FCHUNK;
    for (int i = t; i < FCHUNK; i += 256) {
        int e = base + i;
        int s = esrc[e];
        int d = edst[e];
        float w = av * eval_[e];
        int bk = s >> 6;
        int rank = atomicAdd(&lcnt[bk], 1);
        int pos = lbase[bk] + rank;
        if (pos < (bk + 1) * CAP)              // statistical overflow guard
            staged[pos] = ((u64)(uint)s << 32) | (u64)((uint)d | ((uint)f2bf(w) << 16));
    }
}

// --- K4: fillC+spmm fused — r2 shape (512 thr) + NT staged-load / NT out-store
//         (r7-isolated: fillC 47.0 -> 45.5 us, FETCH 108 -> 104.5 MB) ---
__global__ __launch_bounds__(512) void fillC_spmm(const u64* __restrict__ staged,
                                                  const int* __restrict__ total,
                                                  const ushort* __restrict__ proj,
                                                  float* __restrict__ out) {
    __shared__ uint2 raw[CAP];       // 20 KB
    __shared__ uint  srt[CAP];       // 10 KB
    __shared__ int cnt[64], cur[64], rs[65];
    const int b = blockIdx.x, t = threadIdx.x;
    int n = total[b];
    if (n > CAP) n = CAP;
    if (t < 64) cnt[t] = 0;
    __syncthreads();
    const u64* seg64 = staged + (size_t)b * CAP;
    for (int i = t; i < n; i += 512) {
        u64 v = __builtin_nontemporal_load(&seg64[i]);
        uint2 e = make_uint2((uint)v, (uint)(v >> 32));
        raw[i] = e;
        atomicAdd(&cnt[e.y & 63], 1);
    }
    __syncthreads();
    if (t < 64) cur[t] = cnt[t];
    __syncthreads();
    for (int off = 1; off < 64; off <<= 1) {
        int v = (t < 64 && t >= off) ? cur[t - off] : 0;
        __syncthreads();
        if (t < 64) cur[t] += v;
        __syncthreads();
    }
    if (t < 64) {
        rs[t + 1] = cur[t];                    // inclusive -> row end
        if (t == 0) rs[0] = 0;
        cur[t] -= cnt[t];                      // exclusive row start
    }
    __syncthreads();
    for (int i = t; i < n; i += 512) {
        uint2 e = raw[i];
        int pos = atomicAdd(&cur[e.y & 63], 1);
        srt[pos] = e.x;
    }
    __syncthreads();
    // spmm: 8 waves, wave w owns rows w*8 .. w*8+7
    const int wv = t >> 6;
    const int lane = t & 63;
    for (int rr = 0; rr < 8; ++rr) {
        int r = wv * 8 + rr;
        int beg = rs[r], end = rs[r + 1];
        float ax0 = 0.f, ay0 = 0.f, ax1 = 0.f, ay1 = 0.f;
        int j = beg;
        for (; j + 8 <= end; j += 8) {         // 8 gathers in flight
            uint e[8], u[8];
#pragma unroll
            for (int k = 0; k < 8; ++k) e[k] = srt[j + k];
#pragma unroll
            for (int k = 0; k < 8; ++k)
                u[k] = *(const uint*)&proj[((e[k] & 0xffffu) << 7) + 2 * lane];
#pragma unroll
            for (int k = 0; k < 8; ++k) {
                float w = __uint_as_float(e[k] & 0xffff0000u);
                if (k & 1) {
                    ax1 += w * __uint_as_float(u[k] << 16);
                    ay1 += w * __uint_as_float(u[k] & 0xffff0000u);
                } else {
                    ax0 += w * __uint_as_float(u[k] << 16);
                    ay0 += w * __uint_as_float(u[k] & 0xffff0000u);
                }
            }
        }
        for (; j < end; ++j) {
            uint e = srt[j];
            uint u = *(const uint*)&proj[((e & 0xffffu) << 7) + 2 * lane];
            float w = __uint_as_float(e & 0xffff0000u);
            ax0 += w * __uint_as_float(u << 16);
            ay0 += w * __uint_as_float(u & 0xffff0000u);
        }
        u64 pv = ((u64)__float_as_uint(ay0 + ay1) << 32) | (u64)__float_as_uint(ax0 + ax1);
        __builtin_nontemporal_store(pv,
            (u64*)&out[(((size_t)b * 64 + r) << 7) + 2 * lane]);
    }
}

extern "C" void kernel_launch(void* const* d_in, const int* in_sizes, int n_in,
                              void* d_out, int out_size, void* d_ws, size_t ws_size,
                              hipStream_t stream) {
    const float* ent   = (const float*)d_in[0];
    const float* rel   = (const float*)d_in[1];
    const int*   esrc  = (const int*)d_in[2];
    const int*   edst  = (const int*)d_in[3];
    const float* eval_ = (const float*)d_in[4];
    const float* went  = (const float*)d_in[5];
    const float* w1    = (const float*)d_in[6];
    const float* b1    = (const float*)d_in[7];
    const float* w2    = (const float*)d_in[8];

    float* out      = (float*)d_out;
    float* out_tail = out + (size_t)N_ * F_;

    char* ws = (char*)d_ws;
    size_t off = 0;
    ushort* proj      = (ushort*)(ws + off); off += (size_t)N_ * F_ * 2;       // 10.24 MB
    u64*    staged    = (u64*)(ws + off);    off += (size_t)NBUK * CAP * 8;    // 12.80 MB
    float*  alpha     = (float*)(ws + off);  off += 256;
    int*    hist      = (int*)(ws + off);    off += (size_t)FBLK * NBUK * 4;   // 800 KB
    int*    blockbase = (int*)(ws + off);    off += (size_t)FBLK * NBUK * 4;   // 800 KB (transposed)
    int*    total     = (int*)(ws + off);    off += (size_t)(NBUK + 7) * 4;

    fused_prep<<<950, 256, 0, stream>>>(ent, went, proj, esrc,
                                        rel, out_tail, w1, b1, w2, alpha, hist);
    fillscan_kernel<<<(NBUK + FSTILE - 1) / FSTILE, 256, 0, stream>>>(hist, blockbase, total);
    fillB_kernel<<<FBLK, 256, 0, stream>>>(esrc, edst, eval_, alpha, blockbase, staged);
    fillC_spmm<<<NBUK, 512, 0, stream>>>(staged, total, proj, out);
}

// Round 11
// 177.950 us; speedup vs baseline: 1.1285x; 1.0005x over previous
//
#include <hip/hip_runtime.h>

#define R_ 8
#define N_ 40000
#define F_ 128
#define E_ 160000
#define NE (R_ * E_)        // 1,280,000 edges
#define NBUK 625            // src>>6 buckets of 64 rows; 625*64 == 40000 exactly
#define CAP 2560            // fixed bucket capacity: mean 2048, sigma ~45 -> +11 sigma
#define FBLK 320            // edge chunks
#define FCHUNK 4000         // FBLK * FCHUNK == NE exactly
#define RELCHUNKS (E_ / FCHUNK)   // 40 chunks per relation -> a chunk is single-relation
#define FSTILE 16           // buckets per fillscan tile block

typedef unsigned short ushort;
typedef unsigned int uint;
typedef unsigned long long u64;
typedef __attribute__((ext_vector_type(8))) short bf16x8;
typedef __attribute__((ext_vector_type(4))) float f32x4;

// fp32 -> bf16 round-to-nearest-even (returns bit pattern)
__device__ __forceinline__ ushort f2bf(float x) {
    uint u = __float_as_uint(x);
    return (ushort)((u + 0x7fffu + ((u >> 16) & 1u)) >> 16);
}

// --- K1: fused independent prep (round-2 verbatim — plain cached loads) ---
// blocks [0,625):    proj = ent @ W  via bf16 MFMA (64 rows/block)
// block  625:        rel_mat passthrough to out tail
// blocks [626,630):  alpha MLP (2 relations/block)
// blocks [630,950):  fillA — per-chunk bucket histogram (625 buckets of 64 rows)
__global__ __launch_bounds__(256) void fused_prep(
        const float* __restrict__ ent, const float* __restrict__ W,
        ushort* __restrict__ proj,
        const int* __restrict__ esrc,
        const float* __restrict__ rel, float* __restrict__ out_tail,
        const float* __restrict__ w1, const float* __restrict__ b1,
        const float* __restrict__ w2, float* __restrict__ alpha,
        int* __restrict__ hist) {
    __shared__ float smem[64 * F_];          // 32 KB; aliases as ushort Wt[128][128]
    const int t = threadIdx.x;
    const int b = blockIdx.x;
    if (b < 625) {
        ushort* Wt = (ushort*)smem;          // W^T bf16, chunk-XOR swizzle
#pragma unroll
        for (int p = 0; p < 16; ++p) {
            int k = p * 8 + (t >> 5);
            int c4 = (t & 31) * 4;
            float4 wv = *(const float4*)&W[k * F_ + c4];
#pragma unroll
            for (int i = 0; i < 4; ++i) {
                int col = c4 + i;
                float v = (i == 0) ? wv.x : (i == 1) ? wv.y : (i == 2) ? wv.z : wv.w;
                Wt[col * F_ + ((((k >> 3) ^ (col & 7)) << 3) | (k & 7))] = f2bf(v);
            }
        }
        __syncthreads();
        const int wv_ = t >> 6;              // wave 0..3
        const int lane = t & 63;
        const int m = lane & 15;
        const int q = (lane >> 4) & 3;
        const int row0 = b * 64 + wv_ * 16;
        bf16x8 afrag[4];
        const float* arow = ent + (size_t)(row0 + m) * F_;
#pragma unroll
        for (int kc = 0; kc < 4; ++kc) {
            float4 a0 = *(const float4*)&arow[kc * 32 + q * 8];
            float4 a1 = *(const float4*)&arow[kc * 32 + q * 8 + 4];
            bf16x8 a;
            a[0] = (short)f2bf(a0.x); a[1] = (short)f2bf(a0.y);
            a[2] = (short)f2bf(a0.z); a[3] = (short)f2bf(a0.w);
            a[4] = (short)f2bf(a1.x); a[5] = (short)f2bf(a1.y);
            a[6] = (short)f2bf(a1.z); a[7] = (short)f2bf(a1.w);
            afrag[kc] = a;
        }
        f32x4 acc[8];
#pragma unroll
        for (int ct = 0; ct < 8; ++ct) acc[ct] = (f32x4){0.f, 0.f, 0.f, 0.f};
#pragma unroll
        for (int ct = 0; ct < 8; ++ct) {
            int n = ct * 16 + m;
#pragma unroll
            for (int kc = 0; kc < 4; ++kc) {
                int chunk = kc * 4 + q;
                bf16x8 bfrag = *(const bf16x8*)&Wt[n * F_ + ((chunk ^ (n & 7)) << 3)];
                acc[ct] = __builtin_amdgcn_mfma_f32_16x16x32_bf16(afrag[kc], bfrag, acc[ct], 0, 0, 0);
            }
        }
#pragma unroll
        for (int ct = 0; ct < 8; ++ct) {
#pragma unroll
            for (int reg = 0; reg < 4; ++reg) {
                int row = row0 + q * 4 + reg;
                proj[(size_t)row * F_ + ct * 16 + m] = f2bf(acc[ct][reg]);
            }
        }
    } else if (b == 625) {
        ((float4*)out_tail)[t] = ((const float4*)rel)[t];   // 1024 floats
    } else if (b < 630) {
        int r = (b - 626) * 2 + (t >> 7);
        int o = t & 127;
        float s = 0.f;
#pragma unroll 8
        for (int f = 0; f < F_; ++f) s += rel[r * F_ + f] * w1[f * F_ + o];
        float h = tanhf(s + b1[o]);
        smem[t] = h * w2[o];
        __syncthreads();
        for (int off = 64; off > 0; off >>= 1) {
            if ((t & 127) < off) smem[t] += smem[t + off];
            __syncthreads();
        }
        if ((t & 127) == 0) alpha[r] = 1.f / (1.f + expf(-smem[t]));
    } else {
        // fillA: bucket histogram for chunk hb (LDS int atomics)
        int hb = b - 630;
        int* h = (int*)smem;
        for (int i = t; i < NBUK; i += 256) h[i] = 0;
        __syncthreads();
        int base = hb * FCHUNK;
        for (int i = t; i < FCHUNK; i += 256)
            atomicAdd(&h[esrc[base + i] >> 6], 1);
        __syncthreads();
        for (int i = t; i < NBUK; i += 256) hist[hb * NBUK + i] = h[i];   // coalesced
    }
}

// --- K2: tiled fillscan — load a [320][16]-bucket hist tile coalesced, shfl-scan
//         the 320-chunk prefix per bucket column in LDS, write TRANSPOSED
//         blockbase[chunk][bucket] coalesced. (r10-verified) ---
__global__ __launch_bounds__(256) void fillscan_kernel(const int* __restrict__ hist,
                                                       int* __restrict__ blockbase,
                                                       int* __restrict__ total) {
    __shared__ int sc[FBLK][FSTILE + 1];     // 17-pad: conflict-free column walks
    __shared__ int tot_s[FSTILE];
    const int t = threadIdx.x;
    const int tb = blockIdx.x * FSTILE;
    // load tile (64 B coalesced runs per row)
    for (int i = t; i < FBLK * FSTILE; i += 256) {
        int f = i >> 4;
        int c = i & (FSTILE - 1);
        int bk = tb + c;
        sc[f][c] = (bk < NBUK) ? hist[f * NBUK + bk] : 0;
    }
    __syncthreads();
    // scan each bucket column: 4 waves x 4 columns, 5 shfl-64 segments + carry
    const int wv = t >> 6, lane = t & 63;
    for (int c = wv; c < FSTILE; c += 4) {
        int carry = 0;
#pragma unroll
        for (int seg = 0; seg < FBLK / 64; ++seg) {
            int f = seg * 64 + lane;
            int v = sc[f][c];
            int s = v;
#pragma unroll
            for (int off = 1; off < 64; off <<= 1) {
                int u = __shfl_up(s, off, 64);
                if (lane >= off) s += u;
            }
            sc[f][c] = carry + s - v;        // exclusive, bucket-relative
            carry += __shfl(s, 63, 64);
        }
        if (lane == 0) tot_s[c] = carry;
    }
    __syncthreads();
    // write out transposed layout, coalesced (64 B runs per chunk row)
    for (int i = t; i < FBLK * FSTILE; i += 256) {
        int f = i >> 4;
        int c = i & (FSTILE - 1);
        int bk = tb + c;
        if (bk < NBUK) blockbase[f * NBUK + bk] = sc[f][c];
    }
    if (t < FSTILE && tb + t < NBUK) total[tb + t] = tot_s[t];
}

// --- K3: fillB — THE round-11 change: 1024 threads/block (20 waves/CU, was 5).
//         The scattered 8-B write-allocate stores are latency-bound; 4x wave
//         concurrency quadruples outstanding stores. Plain cached loads/stores
//         (r7/r9 lessons). r5 already validated this config's correctness. ---
__global__ __launch_bounds__(1024) void fillB_kernel(const int* __restrict__ esrc,
                                                     const int* __restrict__ edst,
                                                     const float* __restrict__ eval_,
                                                     const float* __restrict__ alpha,
                                                     const int* __restrict__ blockbase,
                                                     u64* __restrict__ staged) {
    __shared__ int lcnt[NBUK];
    __shared__ int lbase[NBUK];
    int t = threadIdx.x, blk = blockIdx.x;
    for (int i = t; i < NBUK; i += 1024) {
        lcnt[i] = 0;
        lbase[i] = i * CAP + blockbase[blk * NBUK + i];   // coalesced row read
    }
    __syncthreads();
    const float av = alpha[blk / RELCHUNKS];   // chunk is entirely one relation
    int base = blk * FCHUNK;
    for (int i = t; i < FCHUNK; i += 1024) {
        int e = base + i;
        int s = esrc[e];
        int d = edst[e];
        float w = av * eval_[e];
        int bk = s >> 6;
        int rank = atomicAdd(&lcnt[bk], 1);
        int pos = lbase[bk] + rank;
        if (pos < (bk + 1) * CAP)              // statistical overflow guard
            staged[pos] = ((u64)(uint)s << 32) | (u64)((uint)d | ((uint)f2bf(w) << 16));
    }
}

// --- K4: fillC+spmm fused — r10 verbatim (512 thr, NT staged-load / NT out-store;
//         pinned at the ~2.3 TB/s L2-miss service floor: 45.5 us, FETCH 104.5 MB) ---
__global__ __launch_bounds__(512) void fillC_spmm(const u64* __restrict__ staged,
                                                  const int* __restrict__ total,
                                                  const ushort* __restrict__ proj,
                                                  float* __restrict__ out) {
    __shared__ uint2 raw[CAP];       // 20 KB
    __shared__ uint  srt[CAP];       // 10 KB
    __shared__ int cnt[64], cur[64], rs[65];
    const int b = blockIdx.x, t = threadIdx.x;
    int n = total[b];
    if (n > CAP) n = CAP;
    if (t < 64) cnt[t] = 0;
    __syncthreads();
    const u64* seg64 = staged + (size_t)b * CAP;
    for (int i = t; i < n; i += 512) {
        u64 v = __builtin_nontemporal_load(&seg64[i]);
        uint2 e = make_uint2((uint)v, (uint)(v >> 32));
        raw[i] = e;
        atomicAdd(&cnt[e.y & 63], 1);
    }
    __syncthreads();
    if (t < 64) cur[t] = cnt[t];
    __syncthreads();
    for (int off = 1; off < 64; off <<= 1) {
        int v = (t < 64 && t >= off) ? cur[t - off] : 0;
        __syncthreads();
        if (t < 64) cur[t] += v;
        __syncthreads();
    }
    if (t < 64) {
        rs[t + 1] = cur[t];                    // inclusive -> row end
        if (t == 0) rs[0] = 0;
        cur[t] -= cnt[t];                      // exclusive row start
    }
    __syncthreads();
    for (int i = t; i < n; i += 512) {
        uint2 e = raw[i];
        int pos = atomicAdd(&cur[e.y & 63], 1);
        srt[pos] = e.x;
    }
    __syncthreads();
    // spmm: 8 waves, wave w owns rows w*8 .. w*8+7
    const int wv = t >> 6;
    const int lane = t & 63;
    for (int rr = 0; rr < 8; ++rr) {
        int r = wv * 8 + rr;
        int beg = rs[r], end = rs[r + 1];
        float ax0 = 0.f, ay0 = 0.f, ax1 = 0.f, ay1 = 0.f;
        int j = beg;
        for (; j + 8 <= end; j += 8) {         // 8 gathers in flight
            uint e[8], u[8];
#pragma unroll
            for (int k = 0; k < 8; ++k) e[k] = srt[j + k];
#pragma unroll
            for (int k = 0; k < 8; ++k)
                u[k] = *(const uint*)&proj[((e[k] & 0xffffu) << 7) + 2 * lane];
#pragma unroll
            for (int k = 0; k < 8; ++k) {
                float w = __uint_as_float(e[k] & 0xffff0000u);
                if (k & 1) {
                    ax1 += w * __uint_as_float(u[k] << 16);
                    ay1 += w * __uint_as_float(u[k] & 0xffff0000u);
                } else {
                    ax0 += w * __uint_as_float(u[k] << 16);
                    ay0 += w * __uint_as_float(u[k] & 0xffff0000u);
                }
            }
        }
        for (; j < end; ++j) {
            uint e = srt[j];
            uint u = *(const uint*)&proj[((e & 0xffffu) << 7) + 2 * lane];
            float w = __uint_as_float(e & 0xffff0000u);
            ax0 += w * __uint_as_float(u << 16);
            ay0 += w * __uint_as_float(u & 0xffff0000u);
        }
        u64 pv = ((u64)__float_as_uint(ay0 + ay1) << 32) | (u64)__float_as_uint(ax0 + ax1);
        __builtin_nontemporal_store(pv,
            (u64*)&out[(((size_t)b * 64 + r) << 7) + 2 * lane]);
    }
}

extern "C" void kernel_launch(void* const* d_in, const int* in_sizes, int n_in,
                              void* d_out, int out_size, void* d_ws, size_t ws_size,
                              hipStream_t stream) {
    const float* ent   = (const float*)d_in[0];
    const float* rel   = (const float*)d_in[1];
    const int*   esrc  = (const int*)d_in[2];
    const int*   edst  = (const int*)d_in[3];
    const float* eval_ = (const float*)d_in[4];
    const float* went  = (const float*)d_in[5];
    const float* w1    = (const float*)d_in[6];
    const float* b1    = (const float*)d_in[7];
    const float* w2    = (const float*)d_in[8];

    float* out      = (float*)d_out;
    float* out_tail = out + (size_t)N_ * F_;

    char* ws = (char*)d_ws;
    size_t off = 0;
    ushort* proj      = (ushort*)(ws + off); off += (size_t)N_ * F_ * 2;       // 10.24 MB
    u64*    staged    = (u64*)(ws + off);    off += (size_t)NBUK * CAP * 8;    // 12.80 MB
    float*  alpha     = (float*)(ws + off);  off += 256;
    int*    hist      = (int*)(ws + off);    off += (size_t)FBLK * NBUK * 4;   // 800 KB
    int*    blockbase = (int*)(ws + off);    off += (size_t)FBLK * NBUK * 4;   // 800 KB (transposed)
    int*    total     = (int*)(ws + off);    off += (size_t)(NBUK + 7) * 4;

    fused_prep<<<950, 256, 0, stream>>>(ent, went, proj, esrc,
                                        rel, out_tail, w1, b1, w2, alpha, hist);
    fillscan_kernel<<<(NBUK + FSTILE - 1) / FSTILE, 256, 0, stream>>>(hist, blockbase, total);
    fillB_kernel<<<FBLK, 1024, 0, stream>>>(esrc, edst, eval_, alpha, blockbase, staged);
    fillC_spmm<<<NBUK, 512, 0, stream>>>(staged, total, proj, out);
}